// Round 12
// baseline (121.021 us; speedup 1.0000x reference)
//
#include <hip/hip_runtime.h>
#include <math.h>

typedef short bf16x8 __attribute__((ext_vector_type(8)));
typedef float f32x4 __attribute__((ext_vector_type(4)));

#define NPT0 16384
#define NPTF 32768

__device__ __forceinline__ short f2b(float f) {
  union { float f; unsigned u; } v; v.f = f;
  return (short)((v.u + 0x7FFFu + ((v.u >> 16) & 1u)) >> 16);
}
// packed bf16 pair: lo = bf16(a), hi = bf16(b)
__device__ __forceinline__ int cvtpk(float a, float b) {
  int r;
  asm("v_cvt_pk_bf16_f32 %0, %1, %2" : "=v"(r) : "v"(a), "v"(b));
  return r;
}
// tanh(z) = 1 - 2/(exp(2z)+1). Saturates correctly at +-1 (exp->inf/0).
__device__ __forceinline__ float tanh_fast(float z) {
  const float e = __expf(2.f * z);
  return 1.f - 2.f * __builtin_amdgcn_rcpf(e + 1.f);
}
// short-index of element (n, point-col c) inside one 16-pt fragment-linear
// plane region of 4096 shorts: (n>>5)*512 + (((n>>3)&3)*16 + c)*8 + (n&7)
__device__ __forceinline__ int inplane(int n, int c) {
  return ((n >> 5) << 9) + ((((n >> 3) & 3) * 16 + c) << 3) + (n & 7);
}

// ---------------------------------------------------------------------------
// prep: W1..W5 fp32 [k][n] -> packed MFMA A-fragment chunks (Wt),
//       W6 fp32 [k][3]     -> zero-padded A-fragment block (at Wt+5*65536).
// Chunk element (l,e) of [layer][nt][ks]: n = nt*16+(l&15), k = ks*32+(l>>4)*8+e
// ---------------------------------------------------------------------------
__global__ void prep_kernel(const float* __restrict__ W1, const float* __restrict__ W2,
                            const float* __restrict__ W3, const float* __restrict__ W4,
                            const float* __restrict__ W5, const float* __restrict__ W6,
                            short* __restrict__ Wt)
{
  const int i = blockIdx.x * 256 + threadIdx.x;   // 0..331775
  if (i < 5 * 65536) {
    const int layer = i >> 16;
    const float* src = layer == 0 ? W1 : layer == 1 ? W2 : layer == 2 ? W3
                     : layer == 3 ? W4 : W5;
    const int w  = i & 65535;
    const int nt = w >> 12;
    const int ks = (w >> 9) & 7;
    const int l  = (w >> 3) & 63;
    const int e  = w & 7;
    const int n  = nt * 16 + (l & 15);
    const int k  = ks * 32 + (l >> 4) * 8 + e;
    Wt[i] = f2b(src[k * 256 + n]);
  } else {
    const int w  = i - 5 * 65536;   // 0..4095
    const int ks = w >> 9;
    const int l  = (w >> 3) & 63;
    const int e  = w & 7;
    const int n  = l & 15;
    const int k  = ks * 32 + (l >> 4) * 8 + e;
    Wt[i] = (n < 3) ? f2b(W6[k * 3 + n]) : (short)0;
  }
}

// ---------------------------------------------------------------------------
// field: 32 pts/block, 8 waves; wave wv owns n-tiles {wv*2, wv*2+1}.
// act: state s plane at s*8192 shorts, point-group g at +g*4096 (64 KB).
// MFMA: A = W chunk (16 n), B = act (16 pts) -> D[n][p]; 16 MFMA : 2 W loads.
// launch_bounds (512,3): LDS caps residency at 2 blocks/CU anyway; the
// relaxed reg cap (~170) lets the compiler prefetch W/act across ks steps.
// ---------------------------------------------------------------------------
__global__ __launch_bounds__(512, 3) void field_kernel(
    const float* __restrict__ xyz_f,
    const float* __restrict__ lb, const float* __restrict__ ub,
    const float* __restrict__ W0, const float* __restrict__ b0,
    const float* __restrict__ b1, const float* __restrict__ b2,
    const float* __restrict__ b3, const float* __restrict__ b4,
    const float* __restrict__ b5,
    const short* __restrict__ Wt,
    const float* __restrict__ b6,
    float* __restrict__ part_div2, float* __restrict__ part_jxb)
{
  __shared__ short act[4 * 8192];  // 64 KB
  __shared__ float redD[4 * 96];   // [s][o][p]: s*96 + o*32 + p
  const int tid = threadIdx.x;
  const int lane = tid & 63;
  const int wv = tid >> 6;         // 0..7
  const int c = lane & 15;
  const int kg = lane >> 4;

  const float lbx = lb[0], lby = lb[1], lbz = lb[2];
  const float sx = 2.f / (ub[0] - lbx);
  const float sy = 2.f / (ub[1] - lby);
  const float sz = 2.f / (ub[2] - lbz);

  // ---- layer 0 (3 -> 256): thread -> point (tid&31), 16 neurons ----
  {
    const int pp = tid & 15;
    const int pg = (tid >> 4) & 1;
    const int pt = blockIdx.x * 32 + pg * 16 + pp;
    const int n0 = (tid >> 5) * 16;
    const float hx = (xyz_f[pt * 3 + 0] - lbx) * sx - 1.f;
    const float hy = (xyz_f[pt * 3 + 1] - lby) * sy - 1.f;
    const float hz = (xyz_f[pt * 3 + 2] - lbz) * sz - 1.f;
    float th[16], vx[16], vy[16], vz[16];
#pragma unroll
    for (int j = 0; j < 16; ++j) {
      const int n = n0 + j;
      const float w0 = W0[n], w1 = W0[256 + n], w2 = W0[512 + n];
      const float z = b0[n] + hx * w0 + hy * w1 + hz * w2;
      const float t = tanh_fast(z);
      const float g = 1.f - t * t;
      th[j] = t;
      vx[j] = g * sx * w0;
      vy[j] = g * sy * w1;
      vz[j] = g * sz * w2;
    }
    const int ks0 = n0 >> 5;
    const int kgb = (n0 >> 3) & 3;   // 0 or 2
#pragma unroll
    for (int half = 0; half < 2; ++half) {
      const int j0 = half * 8;
      const int idx = pg * 4096 + ks0 * 512 + ((kgb + half) * 16 + pp) * 8;
      int4 o0, o1, o2, o3;
      o0.x = cvtpk(th[j0+0], th[j0+1]); o0.y = cvtpk(th[j0+2], th[j0+3]);
      o0.z = cvtpk(th[j0+4], th[j0+5]); o0.w = cvtpk(th[j0+6], th[j0+7]);
      o1.x = cvtpk(vx[j0+0], vx[j0+1]); o1.y = cvtpk(vx[j0+2], vx[j0+3]);
      o1.z = cvtpk(vx[j0+4], vx[j0+5]); o1.w = cvtpk(vx[j0+6], vx[j0+7]);
      o2.x = cvtpk(vy[j0+0], vy[j0+1]); o2.y = cvtpk(vy[j0+2], vy[j0+3]);
      o2.z = cvtpk(vy[j0+4], vy[j0+5]); o2.w = cvtpk(vy[j0+6], vy[j0+7]);
      o3.x = cvtpk(vz[j0+0], vz[j0+1]); o3.y = cvtpk(vz[j0+2], vz[j0+3]);
      o3.z = cvtpk(vz[j0+4], vz[j0+5]); o3.w = cvtpk(vz[j0+6], vz[j0+7]);
      *(int4*)&act[idx]          = o0;   // plane (0,pg)
      *(int4*)&act[8192 + idx]   = o1;   // plane (1,pg)
      *(int4*)&act[16384 + idx]  = o2;   // plane (2,pg)
      *(int4*)&act[24576 + idx]  = o3;   // plane (3,pg)
    }
  }
  __syncthreads();

  const float* const bsArr[5] = {b1, b2, b3, b4, b5};

#pragma unroll
  for (int layer = 0; layer < 5; ++layer) {
    const short* wbase = Wt + layer * 65536 + (wv * 2) * 4096 + lane * 8;

    f32x4 acc[2][4][2];  // [t][s][g]
#pragma unroll
    for (int t = 0; t < 2; ++t)
#pragma unroll
      for (int s = 0; s < 4; ++s)
#pragma unroll
        for (int g = 0; g < 2; ++g) acc[t][s][g] = (f32x4){0.f, 0.f, 0.f, 0.f};

#pragma unroll
    for (int ks = 0; ks < 8; ++ks) {
      const int sa = ks * 512 + lane * 8;
      const bf16x8 w0 = *(const bf16x8*)(wbase + ks * 512);
      const bf16x8 w1 = *(const bf16x8*)(wbase + 4096 + ks * 512);
      const bf16x8 a00 = *(const bf16x8*)&act[sa];
      const bf16x8 a10 = *(const bf16x8*)&act[8192 + sa];
      const bf16x8 a20 = *(const bf16x8*)&act[16384 + sa];
      const bf16x8 a30 = *(const bf16x8*)&act[24576 + sa];
      const bf16x8 a01 = *(const bf16x8*)&act[4096 + sa];
      const bf16x8 a11 = *(const bf16x8*)&act[12288 + sa];
      const bf16x8 a21 = *(const bf16x8*)&act[20480 + sa];
      const bf16x8 a31 = *(const bf16x8*)&act[28672 + sa];
      __builtin_amdgcn_s_setprio(1);
      acc[0][0][0] = __builtin_amdgcn_mfma_f32_16x16x32_bf16(w0, a00, acc[0][0][0], 0, 0, 0);
      acc[0][1][0] = __builtin_amdgcn_mfma_f32_16x16x32_bf16(w0, a10, acc[0][1][0], 0, 0, 0);
      acc[0][2][0] = __builtin_amdgcn_mfma_f32_16x16x32_bf16(w0, a20, acc[0][2][0], 0, 0, 0);
      acc[0][3][0] = __builtin_amdgcn_mfma_f32_16x16x32_bf16(w0, a30, acc[0][3][0], 0, 0, 0);
      acc[0][0][1] = __builtin_amdgcn_mfma_f32_16x16x32_bf16(w0, a01, acc[0][0][1], 0, 0, 0);
      acc[0][1][1] = __builtin_amdgcn_mfma_f32_16x16x32_bf16(w0, a11, acc[0][1][1], 0, 0, 0);
      acc[0][2][1] = __builtin_amdgcn_mfma_f32_16x16x32_bf16(w0, a21, acc[0][2][1], 0, 0, 0);
      acc[0][3][1] = __builtin_amdgcn_mfma_f32_16x16x32_bf16(w0, a31, acc[0][3][1], 0, 0, 0);
      acc[1][0][0] = __builtin_amdgcn_mfma_f32_16x16x32_bf16(w1, a00, acc[1][0][0], 0, 0, 0);
      acc[1][1][0] = __builtin_amdgcn_mfma_f32_16x16x32_bf16(w1, a10, acc[1][1][0], 0, 0, 0);
      acc[1][2][0] = __builtin_amdgcn_mfma_f32_16x16x32_bf16(w1, a20, acc[1][2][0], 0, 0, 0);
      acc[1][3][0] = __builtin_amdgcn_mfma_f32_16x16x32_bf16(w1, a30, acc[1][3][0], 0, 0, 0);
      acc[1][0][1] = __builtin_amdgcn_mfma_f32_16x16x32_bf16(w1, a01, acc[1][0][1], 0, 0, 0);
      acc[1][1][1] = __builtin_amdgcn_mfma_f32_16x16x32_bf16(w1, a11, acc[1][1][1], 0, 0, 0);
      acc[1][2][1] = __builtin_amdgcn_mfma_f32_16x16x32_bf16(w1, a21, acc[1][2][1], 0, 0, 0);
      acc[1][3][1] = __builtin_amdgcn_mfma_f32_16x16x32_bf16(w1, a31, acc[1][3][1], 0, 0, 0);
      __builtin_amdgcn_s_setprio(0);
    }
    __syncthreads();  // all LDS reads of layer L done

    // epilogue: lane holds point col c (of group g), n = (wv*2+t)*16 + kg*4 + r
    const float* bl = bsArr[layer];
#pragma unroll
    for (int t = 0; t < 2; ++t) {
      const int n0 = (wv * 2 + t) * 16 + kg * 4;
      const f32x4 bias = *(const f32x4*)(bl + n0);
#pragma unroll
      for (int g = 0; g < 2; ++g) {
        float th[4], gd[4];
#pragma unroll
        for (int r = 0; r < 4; ++r) {
          th[r] = tanh_fast(acc[t][0][g][r] + bias[r]);
          gd[r] = 1.f - th[r] * th[r];
        }
        int2 o0, o1, o2, o3;
        o0.x = cvtpk(th[0], th[1]);
        o0.y = cvtpk(th[2], th[3]);
        o1.x = cvtpk(gd[0] * acc[t][1][g][0], gd[1] * acc[t][1][g][1]);
        o1.y = cvtpk(gd[2] * acc[t][1][g][2], gd[3] * acc[t][1][g][3]);
        o2.x = cvtpk(gd[0] * acc[t][2][g][0], gd[1] * acc[t][2][g][1]);
        o2.y = cvtpk(gd[2] * acc[t][2][g][2], gd[3] * acc[t][2][g][3]);
        o3.x = cvtpk(gd[0] * acc[t][3][g][0], gd[1] * acc[t][3][g][1]);
        o3.y = cvtpk(gd[2] * acc[t][3][g][2], gd[3] * acc[t][3][g][3]);
        const int idx = g * 4096 + inplane(n0, c);
        *(int2*)&act[idx]          = o0;
        *(int2*)&act[8192 + idx]   = o1;
        *(int2*)&act[16384 + idx]  = o2;
        *(int2*)&act[24576 + idx]  = o3;
      }
    }
    __syncthreads();  // layer L+1 act complete
  }

  // ---- layer 6 (256 -> 3) via MFMA: wave wv -> state wv>>1, group wv&1 ----
  {
    const int s = wv >> 1, g = wv & 1;
    const short* w6 = Wt + 5 * 65536 + lane * 8;
    f32x4 accT = (f32x4){0.f, 0.f, 0.f, 0.f};
#pragma unroll
    for (int ks = 0; ks < 8; ++ks) {
      const bf16x8 w = *(const bf16x8*)(w6 + ks * 512);
      const bf16x8 b = *(const bf16x8*)&act[s * 8192 + g * 4096 + ks * 512 + lane * 8];
      accT = __builtin_amdgcn_mfma_f32_16x16x32_bf16(w, b, accT, 0, 0, 0);
    }
    if (kg == 0) {
      redD[s * 96 + 0  + g * 16 + c] = accT[0];
      redD[s * 96 + 32 + g * 16 + c] = accT[1];
      redD[s * 96 + 64 + g * 16 + c] = accT[2];
    }
  }
  __syncthreads();
  if (tid < 32) {
    const int p = tid;
    const float bx = redD[0 + p]   + b6[0];
    const float by = redD[32 + p]  + b6[1];
    const float bz = redD[64 + p]  + b6[2];
    const float j00 = redD[96 + p],  j01 = redD[128 + p], j02 = redD[160 + p];
    const float j10 = redD[192 + p], j11 = redD[224 + p], j12 = redD[256 + p];
    const float j20 = redD[288 + p], j21 = redD[320 + p], j22 = redD[352 + p];
    const float dv = j00 + j11 + j22;
    const float jx = j12 - j21;
    const float jy = j20 - j02;
    const float jz = j01 - j10;
    const float e1 = jy * bz - jz * by;
    const float e2 = jz * bx - jx * bz;
    const float e3 = jx * by - jy * bx;
    float d2 = dv * dv;
    float jb = e1 * e1 + e2 * e2 + e3 * e3;
#pragma unroll
    for (int m = 1; m < 32; m <<= 1) {
      d2 += __shfl_xor(d2, m);
      jb += __shfl_xor(jb, m);
    }
    if (tid == 0) {
      part_div2[blockIdx.x] = d2;
      part_jxb[blockIdx.x]  = jb;
    }
  }
}

// ---------------------------------------------------------------------------
// bc: 32 pts/block, 8 waves, 1 state (z=0 plane). Act hoisted to regs so the
// W-load+MFMA+epilogue phase runs barrier-free.
// ---------------------------------------------------------------------------
__global__ __launch_bounds__(512, 4) void bc_kernel(
    const float* __restrict__ x0, const float* __restrict__ y0,
    const float* __restrict__ bx0, const float* __restrict__ by0,
    const float* __restrict__ bz0,
    const float* __restrict__ lb, const float* __restrict__ ub,
    const float* __restrict__ W0, const float* __restrict__ b0,
    const float* __restrict__ b1, const float* __restrict__ b2,
    const float* __restrict__ b3, const float* __restrict__ b4,
    const float* __restrict__ b5,
    const short* __restrict__ Wt,
    const float* __restrict__ b6,
    float* __restrict__ part_bc)
{
  __shared__ short act[8192];  // 16 KB: group g at g*4096
  __shared__ float red[2];
  const int tid = threadIdx.x;
  const int lane = tid & 63;
  const int wv = tid >> 6;
  const int c = lane & 15;
  const int kg = lane >> 4;

  const float lbx = lb[0], lby = lb[1], lbz = lb[2];
  const float sx = 2.f / (ub[0] - lbx);
  const float sy = 2.f / (ub[1] - lby);
  const float sz = 2.f / (ub[2] - lbz);

  // ---- layer 0 ----
  {
    const int pp = tid & 15;
    const int pg = (tid >> 4) & 1;
    const int pt = blockIdx.x * 32 + pg * 16 + pp;
    const int n0 = (tid >> 5) * 16;
    const float hx = (x0[pt] - lbx) * sx - 1.f;
    const float hy = (y0[pt] - lby) * sy - 1.f;
    const float hz = (0.f - lbz) * sz - 1.f;
    float th[16];
#pragma unroll
    for (int j = 0; j < 16; ++j) {
      const int n = n0 + j;
      const float z = b0[n] + hx * W0[n] + hy * W0[256 + n] + hz * W0[512 + n];
      th[j] = tanh_fast(z);
    }
    const int ks0 = n0 >> 5;
    const int kgb = (n0 >> 3) & 3;
#pragma unroll
    for (int half = 0; half < 2; ++half) {
      const int j0 = half * 8;
      int4 o;
      o.x = cvtpk(th[j0+0], th[j0+1]); o.y = cvtpk(th[j0+2], th[j0+3]);
      o.z = cvtpk(th[j0+4], th[j0+5]); o.w = cvtpk(th[j0+6], th[j0+7]);
      *(int4*)&act[pg * 4096 + ks0 * 512 + ((kgb + half) * 16 + pp) * 8] = o;
    }
  }
  __syncthreads();

  const float* const bsArr[5] = {b1, b2, b3, b4, b5};

#pragma unroll
  for (int layer = 0; layer < 5; ++layer) {
    const short* wbase = Wt + layer * 65536 + (wv * 2) * 4096 + lane * 8;

    // hoist act reads (64 VGPRs)
    bf16x8 a[2][8];
#pragma unroll
    for (int g = 0; g < 2; ++g)
#pragma unroll
      for (int ks = 0; ks < 8; ++ks)
        a[g][ks] = *(const bf16x8*)&act[g * 4096 + ks * 512 + lane * 8];
    __syncthreads();  // reads done -> writes below are safe

    f32x4 acc[2][2];  // [t][g]
#pragma unroll
    for (int t = 0; t < 2; ++t)
#pragma unroll
      for (int g = 0; g < 2; ++g) acc[t][g] = (f32x4){0.f, 0.f, 0.f, 0.f};

#pragma unroll
    for (int ks = 0; ks < 8; ++ks) {
      const bf16x8 w0 = *(const bf16x8*)(wbase + ks * 512);
      const bf16x8 w1 = *(const bf16x8*)(wbase + 4096 + ks * 512);
      acc[0][0] = __builtin_amdgcn_mfma_f32_16x16x32_bf16(w0, a[0][ks], acc[0][0], 0, 0, 0);
      acc[0][1] = __builtin_amdgcn_mfma_f32_16x16x32_bf16(w0, a[1][ks], acc[0][1], 0, 0, 0);
      acc[1][0] = __builtin_amdgcn_mfma_f32_16x16x32_bf16(w1, a[0][ks], acc[1][0], 0, 0, 0);
      acc[1][1] = __builtin_amdgcn_mfma_f32_16x16x32_bf16(w1, a[1][ks], acc[1][1], 0, 0, 0);
    }

    const float* bl = bsArr[layer];
#pragma unroll
    for (int t = 0; t < 2; ++t) {
      const int n0 = (wv * 2 + t) * 16 + kg * 4;
      const f32x4 bias = *(const f32x4*)(bl + n0);
#pragma unroll
      for (int g = 0; g < 2; ++g) {
        float th[4];
#pragma unroll
        for (int r = 0; r < 4; ++r) th[r] = tanh_fast(acc[t][g][r] + bias[r]);
        int2 o;
        o.x = cvtpk(th[0], th[1]);
        o.y = cvtpk(th[2], th[3]);
        *(int2*)&act[g * 4096 + inplane(n0, c)] = o;
      }
    }
    __syncthreads();  // act[L+1] complete
  }

  // ---- layer 6 + BC loss via MFMA (waves 0,1 -> groups 0,1) ----
  if (wv < 2) {
    const int g = wv;
    const short* w6 = Wt + 5 * 65536 + lane * 8;
    f32x4 accT = (f32x4){0.f, 0.f, 0.f, 0.f};
#pragma unroll
    for (int ks = 0; ks < 8; ++ks) {
      const bf16x8 w = *(const bf16x8*)(w6 + ks * 512);
      const bf16x8 b = *(const bf16x8*)&act[g * 4096 + ks * 512 + lane * 8];
      accT = __builtin_amdgcn_mfma_f32_16x16x32_bf16(w, b, accT, 0, 0, 0);
    }
    if (lane < 16) {
      const int pt = blockIdx.x * 32 + g * 16 + lane;
      const float ex = accT[0] + b6[0] - bx0[pt];
      const float ey = accT[1] + b6[1] - by0[pt];
      const float ez = accT[2] + b6[2] - bz0[pt];
      float abc = ex * ex + ey * ey + ez * ez;
#pragma unroll
      for (int m = 1; m < 16; m <<= 1) abc += __shfl_xor(abc, m);
      if (lane == 0) red[g] = abc;
    }
  }
  __syncthreads();
  if (tid == 0) part_bc[blockIdx.x] = red[0] + red[1];
}

// ---------------------------------------------------------------------------
// reduce: parts[0,1024)=div2, [1024,2048)=jxb, [2048,2560)=bc
// ---------------------------------------------------------------------------
__global__ void reduce_kernel(const float* __restrict__ parts, float* __restrict__ out)
{
  __shared__ float sdata[12];
  const int tid = threadIdx.x, lane = tid & 63, wv = tid >> 6;
  float d = 0.f, j = 0.f, b = 0.f;
  for (int i = tid; i < 1024; i += 256) { d += parts[i]; j += parts[1024 + i]; }
  for (int i = tid; i < 512; i += 256) b += parts[2048 + i];
  for (int off = 32; off > 0; off >>= 1) {
    d += __shfl_down(d, off);
    j += __shfl_down(j, off);
    b += __shfl_down(b, off);
  }
  if (lane == 0) {
    sdata[wv * 3 + 0] = d;
    sdata[wv * 3 + 1] = j;
    sdata[wv * 3 + 2] = b;
  }
  __syncthreads();
  if (tid == 0) {
    float sd = 0.f, sj = 0.f, sb = 0.f;
    for (int w = 0; w < 4; ++w) {
      sd += sdata[w * 3 + 0];
      sj += sdata[w * 3 + 1];
      sb += sdata[w * 3 + 2];
    }
    out[0] = sb / (float)NPT0 + sd / (float)NPTF + sj / (float)NPTF;
  }
}

extern "C" void kernel_launch(void* const* d_in, const int* in_sizes, int n_in,
                              void* d_out, int out_size, void* d_ws, size_t ws_size,
                              hipStream_t stream)
{
  const float* x0    = (const float*)d_in[0];
  const float* y0    = (const float*)d_in[1];
  const float* bx0   = (const float*)d_in[2];
  const float* by0   = (const float*)d_in[3];
  const float* bz0   = (const float*)d_in[4];
  const float* xyz_f = (const float*)d_in[5];
  const float* lb    = (const float*)d_in[6];
  const float* ub    = (const float*)d_in[7];
  const float* W0 = (const float*)d_in[8];
  const float* b0 = (const float*)d_in[9];
  const float* W1 = (const float*)d_in[10];
  const float* b1 = (const float*)d_in[11];
  const float* W2 = (const float*)d_in[12];
  const float* b2 = (const float*)d_in[13];
  const float* W3 = (const float*)d_in[14];
  const float* b3 = (const float*)d_in[15];
  const float* W4 = (const float*)d_in[16];
  const float* b4 = (const float*)d_in[17];
  const float* W5 = (const float*)d_in[18];
  const float* b5 = (const float*)d_in[19];
  const float* W6 = (const float*)d_in[20];
  const float* b6 = (const float*)d_in[21];

  short* Wt = (short*)d_ws;                          // (5*65536 + 4096) shorts
  float* parts = (float*)((char*)d_ws + (5 * 65536 + 4096) * sizeof(short));
  float* p_div2 = parts;          // 1024
  float* p_jxb  = parts + 1024;   // 1024
  float* p_bc   = parts + 2048;   // 512

  prep_kernel<<<1296, 256, 0, stream>>>(W1, W2, W3, W4, W5, W6, Wt);
  field_kernel<<<1024, 512, 0, stream>>>(xyz_f, lb, ub, W0, b0,
      b1, b2, b3, b4, b5, Wt, b6, p_div2, p_jxb);
  bc_kernel<<<512, 512, 0, stream>>>(x0, y0, bx0, by0, bz0, lb, ub, W0, b0,
      b1, b2, b3, b4, b5, Wt, b6, p_bc);
  reduce_kernel<<<1, 256, 0, stream>>>(parts, (float*)d_out);
}

// Round 13
// 105.096 us; speedup vs baseline: 1.1515x; 1.1515x over previous
//
#include <hip/hip_runtime.h>
#include <math.h>

typedef short bf16x8 __attribute__((ext_vector_type(8)));
typedef float f32x4 __attribute__((ext_vector_type(4)));

#define NPT0 16384
#define NPTF 32768
#define NB_F 1024
#define NB_B 512

__device__ __forceinline__ short f2b(float f) {
  union { float f; unsigned u; } v; v.f = f;
  return (short)((v.u + 0x7FFFu + ((v.u >> 16) & 1u)) >> 16);
}
__device__ __forceinline__ int cvtpk(float a, float b) {
  int r;
  asm("v_cvt_pk_bf16_f32 %0, %1, %2" : "=v"(r) : "v"(a), "v"(b));
  return r;
}
// tanh(z) = 1 - 2/(exp(2z)+1). Saturates correctly at +-1.
__device__ __forceinline__ float tanh_fast(float z) {
  const float e = __expf(2.f * z);
  return 1.f - 2.f * __builtin_amdgcn_rcpf(e + 1.f);
}
// short-index of element (n, point-col c) inside one 16-pt fragment-linear
// plane region of 4096 shorts.
__device__ __forceinline__ int inplane(int n, int c) {
  return ((n >> 5) << 9) + ((((n >> 3) & 3) * 16 + c) << 3) + (n & 7);
}

// ---------------------------------------------------------------------------
// prep: W1..W5 fp32 [k][n] -> packed MFMA A-fragment chunks (Wt),
//       W6 fp32 [k][3]     -> zero-padded A-fragment block (at Wt+5*65536).
// ---------------------------------------------------------------------------
__global__ void prep_kernel(const float* __restrict__ W1, const float* __restrict__ W2,
                            const float* __restrict__ W3, const float* __restrict__ W4,
                            const float* __restrict__ W5, const float* __restrict__ W6,
                            short* __restrict__ Wt)
{
  const int i = blockIdx.x * 256 + threadIdx.x;   // 0..331775
  if (i < 5 * 65536) {
    const int layer = i >> 16;
    const float* src = layer == 0 ? W1 : layer == 1 ? W2 : layer == 2 ? W3
                     : layer == 3 ? W4 : W5;
    const int w  = i & 65535;
    const int nt = w >> 12;
    const int ks = (w >> 9) & 7;
    const int l  = (w >> 3) & 63;
    const int e  = w & 7;
    const int n  = nt * 16 + (l & 15);
    const int k  = ks * 32 + (l >> 4) * 8 + e;
    Wt[i] = f2b(src[k * 256 + n]);
  } else {
    const int w  = i - 5 * 65536;   // 0..4095
    const int ks = w >> 9;
    const int l  = (w >> 3) & 63;
    const int e  = w & 7;
    const int n  = l & 15;
    const int k  = ks * 32 + (l >> 4) * 8 + e;
    Wt[i] = (n < 3) ? f2b(W6[k * 3 + n]) : (short)0;
  }
}

// ---------------------------------------------------------------------------
// fused: blocks [0,NB_F) = field (exact r6 geometry: 32 pts, 8 waves, wave wv
// owns n-tiles {wv*2,wv*2+1} x 4 states x 2 groups; 16 MFMA : 2 W loads);
// blocks [NB_F,NB_F+NB_B) = bc. (512,4) forces the 128-unified-reg budget
// (64 VGPR + 64 AGPR) so 2 blocks/CU stay resident (the r6 cliff-edge).
// ---------------------------------------------------------------------------
__global__ __launch_bounds__(512, 4) void fused_kernel(
    const float* __restrict__ xyz_f,
    const float* __restrict__ x0, const float* __restrict__ y0,
    const float* __restrict__ bx0, const float* __restrict__ by0,
    const float* __restrict__ bz0,
    const float* __restrict__ lb, const float* __restrict__ ub,
    const float* __restrict__ W0, const float* __restrict__ b0,
    const float* __restrict__ b1, const float* __restrict__ b2,
    const float* __restrict__ b3, const float* __restrict__ b4,
    const float* __restrict__ b5,
    const short* __restrict__ Wt,
    const float* __restrict__ b6,
    float* __restrict__ part_div2, float* __restrict__ part_jxb,
    float* __restrict__ part_bc)
{
  __shared__ short act[4 * 8192];  // 64 KB (field); bc uses first 16 KB
  __shared__ float redD[4 * 96];
  const int bid = blockIdx.x;
  const int tid = threadIdx.x;
  const int lane = tid & 63;
  const int wv = tid >> 6;         // 0..7
  const int c = lane & 15;
  const int kg = lane >> 4;

  const float lbx = lb[0], lby = lb[1], lbz = lb[2];
  const float sx = 2.f / (ub[0] - lbx);
  const float sy = 2.f / (ub[1] - lby);
  const float sz = 2.f / (ub[2] - lbz);
  const float* const bsArr[5] = {b1, b2, b3, b4, b5};

  if (bid < NB_F) {
    // =================== FIELD (r6-exact) ===================
    // ---- layer 0 ----
    {
      const int pp = tid & 15;
      const int pg = (tid >> 4) & 1;
      const int pt = bid * 32 + pg * 16 + pp;
      const int n0 = (tid >> 5) * 16;
      const float hx = (xyz_f[pt * 3 + 0] - lbx) * sx - 1.f;
      const float hy = (xyz_f[pt * 3 + 1] - lby) * sy - 1.f;
      const float hz = (xyz_f[pt * 3 + 2] - lbz) * sz - 1.f;
      float th[16], vx[16], vy[16], vz[16];
#pragma unroll
      for (int j = 0; j < 16; ++j) {
        const int n = n0 + j;
        const float w0 = W0[n], w1 = W0[256 + n], w2 = W0[512 + n];
        const float z = b0[n] + hx * w0 + hy * w1 + hz * w2;
        const float t = tanh_fast(z);
        const float g = 1.f - t * t;
        th[j] = t;
        vx[j] = g * sx * w0;
        vy[j] = g * sy * w1;
        vz[j] = g * sz * w2;
      }
      const int ks0 = n0 >> 5;
      const int kgb = (n0 >> 3) & 3;
#pragma unroll
      for (int half = 0; half < 2; ++half) {
        const int j0 = half * 8;
        const int idx = pg * 4096 + ks0 * 512 + ((kgb + half) * 16 + pp) * 8;
        int4 o0, o1, o2, o3;
        o0.x = cvtpk(th[j0+0], th[j0+1]); o0.y = cvtpk(th[j0+2], th[j0+3]);
        o0.z = cvtpk(th[j0+4], th[j0+5]); o0.w = cvtpk(th[j0+6], th[j0+7]);
        o1.x = cvtpk(vx[j0+0], vx[j0+1]); o1.y = cvtpk(vx[j0+2], vx[j0+3]);
        o1.z = cvtpk(vx[j0+4], vx[j0+5]); o1.w = cvtpk(vx[j0+6], vx[j0+7]);
        o2.x = cvtpk(vy[j0+0], vy[j0+1]); o2.y = cvtpk(vy[j0+2], vy[j0+3]);
        o2.z = cvtpk(vy[j0+4], vy[j0+5]); o2.w = cvtpk(vy[j0+6], vy[j0+7]);
        o3.x = cvtpk(vz[j0+0], vz[j0+1]); o3.y = cvtpk(vz[j0+2], vz[j0+3]);
        o3.z = cvtpk(vz[j0+4], vz[j0+5]); o3.w = cvtpk(vz[j0+6], vz[j0+7]);
        *(int4*)&act[idx]          = o0;
        *(int4*)&act[8192 + idx]   = o1;
        *(int4*)&act[16384 + idx]  = o2;
        *(int4*)&act[24576 + idx]  = o3;
      }
    }
    __syncthreads();

#pragma unroll
    for (int layer = 0; layer < 5; ++layer) {
      const short* wbase = Wt + layer * 65536 + (wv * 2) * 4096 + lane * 8;

      f32x4 acc[2][4][2];  // [t][s][g]
#pragma unroll
      for (int t = 0; t < 2; ++t)
#pragma unroll
        for (int s = 0; s < 4; ++s)
#pragma unroll
          for (int g = 0; g < 2; ++g) acc[t][s][g] = (f32x4){0.f, 0.f, 0.f, 0.f};

#pragma unroll
      for (int ks = 0; ks < 8; ++ks) {
        const int sa = ks * 512 + lane * 8;
        const bf16x8 w0 = *(const bf16x8*)(wbase + ks * 512);
        const bf16x8 w1 = *(const bf16x8*)(wbase + 4096 + ks * 512);
#pragma unroll
        for (int g = 0; g < 2; ++g) {
          const bf16x8 a0 = *(const bf16x8*)&act[g * 4096 + sa];
          const bf16x8 a1 = *(const bf16x8*)&act[8192 + g * 4096 + sa];
          const bf16x8 a2 = *(const bf16x8*)&act[16384 + g * 4096 + sa];
          const bf16x8 a3 = *(const bf16x8*)&act[24576 + g * 4096 + sa];
          acc[0][0][g] = __builtin_amdgcn_mfma_f32_16x16x32_bf16(w0, a0, acc[0][0][g], 0, 0, 0);
          acc[0][1][g] = __builtin_amdgcn_mfma_f32_16x16x32_bf16(w0, a1, acc[0][1][g], 0, 0, 0);
          acc[0][2][g] = __builtin_amdgcn_mfma_f32_16x16x32_bf16(w0, a2, acc[0][2][g], 0, 0, 0);
          acc[0][3][g] = __builtin_amdgcn_mfma_f32_16x16x32_bf16(w0, a3, acc[0][3][g], 0, 0, 0);
          acc[1][0][g] = __builtin_amdgcn_mfma_f32_16x16x32_bf16(w1, a0, acc[1][0][g], 0, 0, 0);
          acc[1][1][g] = __builtin_amdgcn_mfma_f32_16x16x32_bf16(w1, a1, acc[1][1][g], 0, 0, 0);
          acc[1][2][g] = __builtin_amdgcn_mfma_f32_16x16x32_bf16(w1, a2, acc[1][2][g], 0, 0, 0);
          acc[1][3][g] = __builtin_amdgcn_mfma_f32_16x16x32_bf16(w1, a3, acc[1][3][g], 0, 0, 0);
        }
      }
      __syncthreads();  // all LDS reads of layer L done

      const float* bl = bsArr[layer];
#pragma unroll
      for (int t = 0; t < 2; ++t) {
        const int n0 = (wv * 2 + t) * 16 + kg * 4;
        const f32x4 bias = *(const f32x4*)(bl + n0);
#pragma unroll
        for (int g = 0; g < 2; ++g) {
          float th[4], gd[4];
#pragma unroll
          for (int r = 0; r < 4; ++r) {
            th[r] = tanh_fast(acc[t][0][g][r] + bias[r]);
            gd[r] = 1.f - th[r] * th[r];
          }
          int2 o0, o1, o2, o3;
          o0.x = cvtpk(th[0], th[1]);
          o0.y = cvtpk(th[2], th[3]);
          o1.x = cvtpk(gd[0] * acc[t][1][g][0], gd[1] * acc[t][1][g][1]);
          o1.y = cvtpk(gd[2] * acc[t][1][g][2], gd[3] * acc[t][1][g][3]);
          o2.x = cvtpk(gd[0] * acc[t][2][g][0], gd[1] * acc[t][2][g][1]);
          o2.y = cvtpk(gd[2] * acc[t][2][g][2], gd[3] * acc[t][2][g][3]);
          o3.x = cvtpk(gd[0] * acc[t][3][g][0], gd[1] * acc[t][3][g][1]);
          o3.y = cvtpk(gd[2] * acc[t][3][g][2], gd[3] * acc[t][3][g][3]);
          const int idx = g * 4096 + inplane(n0, c);
          *(int2*)&act[idx]          = o0;
          *(int2*)&act[8192 + idx]   = o1;
          *(int2*)&act[16384 + idx]  = o2;
          *(int2*)&act[24576 + idx]  = o3;
        }
      }
      __syncthreads();  // layer L+1 act complete
    }

    // ---- layer 6 + physics ----
    {
      const int s = wv >> 1, g = wv & 1;
      const short* w6 = Wt + 5 * 65536 + lane * 8;
      f32x4 accT = (f32x4){0.f, 0.f, 0.f, 0.f};
#pragma unroll
      for (int ks = 0; ks < 8; ++ks) {
        const bf16x8 w = *(const bf16x8*)(w6 + ks * 512);
        const bf16x8 b = *(const bf16x8*)&act[s * 8192 + g * 4096 + ks * 512 + lane * 8];
        accT = __builtin_amdgcn_mfma_f32_16x16x32_bf16(w, b, accT, 0, 0, 0);
      }
      if (kg == 0) {
        redD[s * 96 + 0  + g * 16 + c] = accT[0];
        redD[s * 96 + 32 + g * 16 + c] = accT[1];
        redD[s * 96 + 64 + g * 16 + c] = accT[2];
      }
    }
    __syncthreads();
    if (tid < 32) {
      const int p = tid;
      const float bx = redD[0 + p]   + b6[0];
      const float by = redD[32 + p]  + b6[1];
      const float bz = redD[64 + p]  + b6[2];
      const float j00 = redD[96 + p],  j01 = redD[128 + p], j02 = redD[160 + p];
      const float j10 = redD[192 + p], j11 = redD[224 + p], j12 = redD[256 + p];
      const float j20 = redD[288 + p], j21 = redD[320 + p], j22 = redD[352 + p];
      const float dv = j00 + j11 + j22;
      const float jx = j12 - j21;
      const float jy = j20 - j02;
      const float jz = j01 - j10;
      const float e1 = jy * bz - jz * by;
      const float e2 = jz * bx - jx * bz;
      const float e3 = jx * by - jy * bx;
      float d2 = dv * dv;
      float jb = e1 * e1 + e2 * e2 + e3 * e3;
#pragma unroll
      for (int m = 1; m < 32; m <<= 1) {
        d2 += __shfl_xor(d2, m);
        jb += __shfl_xor(jb, m);
      }
      if (tid == 0) {
        part_div2[bid] = d2;
        part_jxb[bid]  = jb;
      }
    }
    return;
  }

  // =================== BC (r6-exact) ===================
  const int bb = bid - NB_F;

  // ---- layer 0 ----
  {
    const int pp = tid & 15;
    const int pg = (tid >> 4) & 1;
    const int pt = bb * 32 + pg * 16 + pp;
    const int n0 = (tid >> 5) * 16;
    const float hx = (x0[pt] - lbx) * sx - 1.f;
    const float hy = (y0[pt] - lby) * sy - 1.f;
    const float hz = (0.f - lbz) * sz - 1.f;
    float th[16];
#pragma unroll
    for (int j = 0; j < 16; ++j) {
      const int n = n0 + j;
      const float z = b0[n] + hx * W0[n] + hy * W0[256 + n] + hz * W0[512 + n];
      th[j] = tanh_fast(z);
    }
    const int ks0 = n0 >> 5;
    const int kgb = (n0 >> 3) & 3;
#pragma unroll
    for (int half = 0; half < 2; ++half) {
      const int j0 = half * 8;
      int4 o;
      o.x = cvtpk(th[j0+0], th[j0+1]); o.y = cvtpk(th[j0+2], th[j0+3]);
      o.z = cvtpk(th[j0+4], th[j0+5]); o.w = cvtpk(th[j0+6], th[j0+7]);
      *(int4*)&act[pg * 4096 + ks0 * 512 + ((kgb + half) * 16 + pp) * 8] = o;
    }
  }
  __syncthreads();

#pragma unroll
  for (int layer = 0; layer < 5; ++layer) {
    const short* wbase = Wt + layer * 65536 + (wv * 2) * 4096 + lane * 8;

    bf16x8 a[2][8];
#pragma unroll
    for (int g = 0; g < 2; ++g)
#pragma unroll
      for (int ks = 0; ks < 8; ++ks)
        a[g][ks] = *(const bf16x8*)&act[g * 4096 + ks * 512 + lane * 8];
    __syncthreads();

    f32x4 acc[2][2];
#pragma unroll
    for (int t = 0; t < 2; ++t)
#pragma unroll
      for (int g = 0; g < 2; ++g) acc[t][g] = (f32x4){0.f, 0.f, 0.f, 0.f};

#pragma unroll
    for (int ks = 0; ks < 8; ++ks) {
      const bf16x8 w0 = *(const bf16x8*)(wbase + ks * 512);
      const bf16x8 w1 = *(const bf16x8*)(wbase + 4096 + ks * 512);
      acc[0][0] = __builtin_amdgcn_mfma_f32_16x16x32_bf16(w0, a[0][ks], acc[0][0], 0, 0, 0);
      acc[0][1] = __builtin_amdgcn_mfma_f32_16x16x32_bf16(w0, a[1][ks], acc[0][1], 0, 0, 0);
      acc[1][0] = __builtin_amdgcn_mfma_f32_16x16x32_bf16(w1, a[0][ks], acc[1][0], 0, 0, 0);
      acc[1][1] = __builtin_amdgcn_mfma_f32_16x16x32_bf16(w1, a[1][ks], acc[1][1], 0, 0, 0);
    }

    const float* bl = bsArr[layer];
#pragma unroll
    for (int t = 0; t < 2; ++t) {
      const int n0 = (wv * 2 + t) * 16 + kg * 4;
      const f32x4 bias = *(const f32x4*)(bl + n0);
#pragma unroll
      for (int g = 0; g < 2; ++g) {
        float th[4];
#pragma unroll
        for (int r = 0; r < 4; ++r) th[r] = tanh_fast(acc[t][g][r] + bias[r]);
        int2 o;
        o.x = cvtpk(th[0], th[1]);
        o.y = cvtpk(th[2], th[3]);
        *(int2*)&act[g * 4096 + inplane(n0, c)] = o;
      }
    }
    __syncthreads();
  }

  // ---- layer 6 + BC loss ----
  if (wv < 2) {
    const int g = wv;
    const short* w6 = Wt + 5 * 65536 + lane * 8;
    f32x4 accT = (f32x4){0.f, 0.f, 0.f, 0.f};
#pragma unroll
    for (int ks = 0; ks < 8; ++ks) {
      const bf16x8 w = *(const bf16x8*)(w6 + ks * 512);
      const bf16x8 b = *(const bf16x8*)&act[g * 4096 + ks * 512 + lane * 8];
      accT = __builtin_amdgcn_mfma_f32_16x16x32_bf16(w, b, accT, 0, 0, 0);
    }
    if (lane < 16) {
      const int pt = bb * 32 + g * 16 + lane;
      const float ex = accT[0] + b6[0] - bx0[pt];
      const float ey = accT[1] + b6[1] - by0[pt];
      const float ez = accT[2] + b6[2] - bz0[pt];
      float abc = ex * ex + ey * ey + ez * ez;
#pragma unroll
      for (int m = 1; m < 16; m <<= 1) abc += __shfl_xor(abc, m);
      if (lane == 0) redD[g] = abc;
    }
  }
  __syncthreads();
  if (tid == 0) part_bc[bb] = redD[0] + redD[1];
}

// ---------------------------------------------------------------------------
// reduce: parts[0,1024)=div2, [1024,2048)=jxb, [2048,2560)=bc
// ---------------------------------------------------------------------------
__global__ void reduce_kernel(const float* __restrict__ parts, float* __restrict__ out)
{
  __shared__ float sdata[12];
  const int tid = threadIdx.x, lane = tid & 63, wv = tid >> 6;
  float d = 0.f, j = 0.f, b = 0.f;
  for (int i = tid; i < 1024; i += 256) { d += parts[i]; j += parts[1024 + i]; }
  for (int i = tid; i < 512; i += 256) b += parts[2048 + i];
  for (int off = 32; off > 0; off >>= 1) {
    d += __shfl_down(d, off);
    j += __shfl_down(j, off);
    b += __shfl_down(b, off);
  }
  if (lane == 0) {
    sdata[wv * 3 + 0] = d;
    sdata[wv * 3 + 1] = j;
    sdata[wv * 3 + 2] = b;
  }
  __syncthreads();
  if (tid == 0) {
    float sd = 0.f, sj = 0.f, sb = 0.f;
    for (int w = 0; w < 4; ++w) {
      sd += sdata[w * 3 + 0];
      sj += sdata[w * 3 + 1];
      sb += sdata[w * 3 + 2];
    }
    out[0] = sb / (float)NPT0 + sd / (float)NPTF + sj / (float)NPTF;
  }
}

extern "C" void kernel_launch(void* const* d_in, const int* in_sizes, int n_in,
                              void* d_out, int out_size, void* d_ws, size_t ws_size,
                              hipStream_t stream)
{
  const float* x0    = (const float*)d_in[0];
  const float* y0    = (const float*)d_in[1];
  const float* bx0   = (const float*)d_in[2];
  const float* by0   = (const float*)d_in[3];
  const float* bz0   = (const float*)d_in[4];
  const float* xyz_f = (const float*)d_in[5];
  const float* lb    = (const float*)d_in[6];
  const float* ub    = (const float*)d_in[7];
  const float* W0 = (const float*)d_in[8];
  const float* b0 = (const float*)d_in[9];
  const float* W1 = (const float*)d_in[10];
  const float* b1 = (const float*)d_in[11];
  const float* W2 = (const float*)d_in[12];
  const float* b2 = (const float*)d_in[13];
  const float* W3 = (const float*)d_in[14];
  const float* b3 = (const float*)d_in[15];
  const float* W4 = (const float*)d_in[16];
  const float* b4 = (const float*)d_in[17];
  const float* W5 = (const float*)d_in[18];
  const float* b5 = (const float*)d_in[19];
  const float* W6 = (const float*)d_in[20];
  const float* b6 = (const float*)d_in[21];

  short* Wt = (short*)d_ws;                          // (5*65536 + 4096) shorts
  float* parts = (float*)((char*)d_ws + (5 * 65536 + 4096) * sizeof(short));
  float* p_div2 = parts;          // 1024
  float* p_jxb  = parts + 1024;   // 1024
  float* p_bc   = parts + 2048;   // 512

  prep_kernel<<<1296, 256, 0, stream>>>(W1, W2, W3, W4, W5, W6, Wt);
  fused_kernel<<<NB_F + NB_B, 512, 0, stream>>>(xyz_f, x0, y0, bx0, by0, bz0,
      lb, ub, W0, b0, b1, b2, b3, b4, b5, Wt, b6, p_div2, p_jxb, p_bc);
  reduce_kernel<<<1, 256, 0, stream>>>(parts, (float*)d_out);
}